// Round 1
// baseline (2123.964 us; speedup 1.0000x reference)
//
#include <hip/hip_runtime.h>
#include <hip/hip_bf16.h>

typedef __hip_bfloat16 bf16;

static __device__ __forceinline__ float b2f(bf16 x){ return __bfloat162float(x); }
static __device__ __forceinline__ bf16  f2b(float x){ return __float2bfloat16(x); }

constexpr int cB = 2048, cN = 64, cD = 128, cDM = 256, cH = 8, cNE = 6;
constexpr int cBN = cB * cN;                 // 131072 rows
constexpr float LNEPS = 1e-5f;
constexpr float RSQ32 = 0.17677669529663687f; // 1/sqrt(32)
constexpr int WPAD = 260;                     // LDS stride: 260%32==4 (low write conflict), 16B-aligned rows
constexpr int MAXTILES = 8200;                // >= 131072/16 + 6

// ---------------- init: zero etype counters ----------------
__global__ void k_init(int* cnt){ if (threadIdx.x < cNE) cnt[threadIdx.x] = 0; }

// ---------------- qcat[b] = [ln1(src[b]), src_t[b]] ----------------
__global__ __launch_bounds__(256) void k_qprep(const float* __restrict__ src,
        const float* __restrict__ src_t, const float* __restrict__ g1,
        const float* __restrict__ b1, float* __restrict__ qcat){
    int lane = threadIdx.x & 63;
    int b = blockIdx.x * 4 + (threadIdx.x >> 6);
    const float* s = src + b * cD;
    float x0 = s[lane], x1 = s[lane + 64];
    float sm = x0 + x1;
    #pragma unroll
    for (int m = 32; m; m >>= 1) sm += __shfl_xor(sm, m);
    float mu = sm * (1.0f / cD);
    float d0 = x0 - mu, d1 = x1 - mu;
    float vs = d0 * d0 + d1 * d1;
    #pragma unroll
    for (int m = 32; m; m >>= 1) vs += __shfl_xor(vs, m);
    float rs = rsqrtf(vs * (1.0f / cD) + LNEPS);
    float* q = qcat + b * cDM;
    q[lane]        = d0 * rs * g1[lane] + b1[lane];
    q[lane + 64]   = d1 * rs * g1[lane + 64] + b1[lane + 64];
    q[cD + lane]      = src_t[b * cD + lane];
    q[cD + lane + 64] = src_t[b * cD + lane + 64];
}

// ------------- kvec[row] = [ln2(seq+seq_e), seq_t]; scatter row into etype list -------------
__global__ __launch_bounds__(256) void k_kprep(const float* __restrict__ seq,
        const float* __restrict__ seq_t, const float* __restrict__ seq_e,
        const float* __restrict__ g2, const float* __restrict__ b2v,
        const int* __restrict__ etype, bf16* __restrict__ kvec,
        int* __restrict__ cnt, int* __restrict__ eidx){
    int l = threadIdx.x & 31;
    int row = blockIdx.x * 8 + (threadIdx.x >> 5);
    const float* sq = seq + row * cD;
    const float* se = seq_e + row * cD;
    float x[4], sm = 0.f;
    #pragma unroll
    for (int j = 0; j < 4; ++j){ x[j] = sq[l + 32 * j] + se[l + 32 * j]; sm += x[j]; }
    #pragma unroll
    for (int m = 16; m; m >>= 1) sm += __shfl_xor(sm, m);
    float mu = sm * (1.0f / cD), vs = 0.f;
    #pragma unroll
    for (int j = 0; j < 4; ++j){ x[j] -= mu; vs += x[j] * x[j]; }
    #pragma unroll
    for (int m = 16; m; m >>= 1) vs += __shfl_xor(vs, m);
    float rs = rsqrtf(vs * (1.0f / cD) + LNEPS);
    bf16* kv = kvec + (size_t)row * cDM;
    #pragma unroll
    for (int j = 0; j < 4; ++j) kv[l + 32 * j] = f2b(x[j] * rs * g2[l + 32 * j] + b2v[l + 32 * j]);
    #pragma unroll
    for (int j = 0; j < 4; ++j) kv[cD + l + 32 * j] = f2b(seq_t[row * cD + l + 32 * j]);
    if (l == 0){
        int e = etype[row];
        int pos = atomicAdd(cnt + e, 1);
        eidx[e * cBN + pos] = row;
    }
}

// ------------- Qe[b][e] = qcat[b] @ Wq[e].T  (all 6 e per b; q is n-invariant) -------------
__global__ __launch_bounds__(256) void k_qe(const float* __restrict__ qcat,
        const float* __restrict__ Wq, float* __restrict__ Qe){
    __shared__ float q8[8][cDM];
    int t = threadIdx.x, e = blockIdx.y, b0 = blockIdx.x * 8;
    #pragma unroll
    for (int r = 0; r < 8; ++r) q8[r][t] = qcat[(b0 + r) * cDM + t];
    __syncthreads();
    float acc[8] = {};
    const float* w = Wq + ((size_t)e * cDM + t) * cDM;
    for (int kk = 0; kk < cDM; ++kk){
        float wv = w[kk];
        #pragma unroll
        for (int r = 0; r < 8; ++r) acc[r] = fmaf(wv, q8[r][kk], acc[r]);
    }
    #pragma unroll
    for (int r = 0; r < 8; ++r) Qe[((size_t)(b0 + r) * cNE + e) * cDM + t] = acc[r];
}

// ------------- build tile list: (e, tile-within-e) packed -------------
__global__ void k_tiles(const int* __restrict__ cnt, int* __restrict__ tiles,
                        int* __restrict__ ntiles){
    __shared__ int off[cNE + 1];
    if (threadIdx.x == 0){
        int s = 0;
        for (int e = 0; e < cNE; ++e){ off[e] = s; s += (cnt[e] + 15) >> 4; }
        off[cNE] = s;
        *ntiles = s;
    }
    __syncthreads();
    int nt = off[cNE];
    for (int i = threadIdx.x; i < nt; i += blockDim.x){
        int e = 0;
        while (off[e + 1] <= i) ++e;
        tiles[i] = (e << 16) | (i - off[e]);
    }
}

// ------------- grouped K/V projection + attention logits -------------
// Block: one etype-tile of 16 gathered rows, all 256 output cols, K=256.
// Thread tile: 4 rows (by wave) x 4 cols (by lane). K never stored: dotted
// against Qe immediately -> logits. V stored bf16.
__global__ __launch_bounds__(256) void k_heavy(const bf16* __restrict__ kvec,
        const float* __restrict__ Wk, const float* __restrict__ Wv,
        const float* __restrict__ Qe, const float* __restrict__ rpri,
        const int* __restrict__ utype, const int* __restrict__ maskp,
        const int* __restrict__ cnt, const int* __restrict__ eidx,
        const int* __restrict__ tiles, const int* __restrict__ ntiles,
        float* __restrict__ logits, bf16* __restrict__ Vmat){
    __shared__ __align__(16) float wT[32 * WPAD];
    __shared__ __align__(16) float kT[32 * 16];
    __shared__ int s_row[16], s_qo[16], s_msk[16], s_valid[16];
    __shared__ float s_pri[16];
    if ((int)blockIdx.x >= *ntiles) return;
    int t = threadIdx.x;
    int info = tiles[blockIdx.x];
    int e = info >> 16;
    int r0 = (info & 0xffff) * 16;
    if (t < 16){
        int ce = cnt[e];
        int nr = min(16, ce - r0);
        int valid = (t < nr) ? 1 : 0;
        int row = eidx[e * cBN + (valid ? r0 + t : r0)];
        s_row[t] = row; s_valid[t] = valid;
        int b = row >> 6;
        s_qo[t] = (b * cNE + e) * cDM;
        s_pri[t] = rpri[utype[b] * cNE + e];
        s_msk[t] = maskp[row];
    }
    __syncthreads();
    int lane = t & 63;
    int wrow0 = (t >> 6) * 4;  // wave owns 4 rows
    int c0 = lane * 4;         // lane owns 4 cols
    float accK[4][4] = {}, accV[4][4] = {};
    const float* WKb = Wk + (size_t)e * cDM * cDM;
    const float* WVb = Wv + (size_t)e * cDM * cDM;
    for (int ks = 0; ks < 8; ++ks){
        // stage 16 k-rows' K-slice, transposed [kkl][r], f32
        #pragma unroll
        for (int i = 0; i < 2; ++i){
            int idx = t + i * 256;
            int r = idx >> 5, kkl = idx & 31;
            kT[kkl * 16 + r] = b2f(kvec[(size_t)s_row[r] * cDM + ks * 32 + kkl]);
        }
        // stage Wk slice transposed [kkl][c]
        #pragma unroll
        for (int i = 0; i < 32; ++i){
            int idx = t + i * 256;
            int c = idx >> 5, kkl = idx & 31;
            wT[kkl * WPAD + c] = WKb[c * cDM + ks * 32 + kkl];
        }
        __syncthreads();
        #pragma unroll
        for (int kkl = 0; kkl < 32; ++kkl){
            float4 wk = *(const float4*)&wT[kkl * WPAD + c0];
            float4 xv = *(const float4*)&kT[kkl * 16 + wrow0];
            float wkv[4] = {wk.x, wk.y, wk.z, wk.w};
            float xvv[4] = {xv.x, xv.y, xv.z, xv.w};
            #pragma unroll
            for (int r = 0; r < 4; ++r)
                #pragma unroll
                for (int c = 0; c < 4; ++c)
                    accK[r][c] = fmaf(xvv[r], wkv[c], accK[r][c]);
        }
        __syncthreads();
        // stage Wv slice (reuse wT)
        #pragma unroll
        for (int i = 0; i < 32; ++i){
            int idx = t + i * 256;
            int c = idx >> 5, kkl = idx & 31;
            wT[kkl * WPAD + c] = WVb[c * cDM + ks * 32 + kkl];
        }
        __syncthreads();
        #pragma unroll
        for (int kkl = 0; kkl < 32; ++kkl){
            float4 wv = *(const float4*)&wT[kkl * WPAD + c0];
            float4 xv = *(const float4*)&kT[kkl * 16 + wrow0];
            float wvv[4] = {wv.x, wv.y, wv.z, wv.w};
            float xvv[4] = {xv.x, xv.y, xv.z, xv.w};
            #pragma unroll
            for (int r = 0; r < 4; ++r)
                #pragma unroll
                for (int c = 0; c < 4; ++c)
                    accV[r][c] = fmaf(xvv[r], wvv[c], accV[r][c]);
        }
        __syncthreads();
    }
    // epilogue: logits (K dotted with Qe, reduced over the 8-lane head group) + V store
    int hgrp = lane >> 3;  // head id: cols c0..c0+3 lie in head (4*lane)/32
    #pragma unroll
    for (int r = 0; r < 4; ++r){
        int rr = wrow0 + r;
        int row = s_row[rr];
        float part = 0.f;
        const float* qp = Qe + s_qo[rr] + c0;
        #pragma unroll
        for (int c = 0; c < 4; ++c) part = fmaf(accK[r][c], qp[c], part);
        part += __shfl_xor(part, 4);
        part += __shfl_xor(part, 2);
        part += __shfl_xor(part, 1);
        if (s_valid[rr]){
            if ((lane & 7) == 0){
                float lg = s_msk[rr] ? -1e10f : part * s_pri[rr] * RSQ32;
                logits[((size_t)hgrp * cB + (row >> 6)) * cN + (row & 63)] = lg;
            }
            bf16* vp = Vmat + (size_t)row * cDM + c0;
            #pragma unroll
            for (int c = 0; c < 4; ++c) vp[c] = f2b(accV[r][c]);
        }
    }
}

// ------------- softmax, attn out, V-weighted sum, fc, ln3, mlp -------------
__global__ __launch_bounds__(256) void k_final(const float* __restrict__ logits,
        const bf16* __restrict__ Vmat, const float* __restrict__ src,
        const float* __restrict__ fc_w, const float* __restrict__ fc_b,
        const float* __restrict__ g3, const float* __restrict__ b3,
        const float* __restrict__ m1w, const float* __restrict__ m1b,
        const float* __restrict__ m2w, const float* __restrict__ m2b,
        const int* __restrict__ utype,
        float* __restrict__ outF, float* __restrict__ outA){
    __shared__ float p[cH][cN];
    __shared__ float ov[cDM];
    __shared__ float cat[cDM + cD];
    __shared__ float hm[cD];
    __shared__ float red[8];
    int b = blockIdx.x, t = threadIdx.x;
    int h = t >> 5, i = t & 31;
    const float* lgp = logits + ((size_t)h * cB + b) * cN;
    float l0 = lgp[i], l1 = lgp[i + 32];
    float mx = fmaxf(l0, l1);
    #pragma unroll
    for (int m = 16; m; m >>= 1) mx = fmaxf(mx, __shfl_xor(mx, m));
    float e0 = expf(l0 - mx), e1 = expf(l1 - mx);
    float sm = e0 + e1;
    #pragma unroll
    for (int m = 16; m; m >>= 1) sm += __shfl_xor(sm, m);
    float inv = 1.0f / sm;
    e0 *= inv; e1 *= inv;
    p[h][i] = e0; p[h][i + 32] = e1;
    float* ap = outA + ((size_t)h * cB + b) * cN;
    ap[i] = e0; ap[i + 32] = e1;
    __syncthreads();
    // attn-weighted V: col t belongs to head t>>5
    float acc = 0.f;
    const bf16* vb = Vmat + (size_t)b * cN * cDM + t;
    #pragma unroll 4
    for (int n = 0; n < cN; ++n) acc = fmaf(p[h][n], b2f(vb[(size_t)n * cDM]), acc);
    ov[t] = acc;
    __syncthreads();
    // fc by utype
    int u = utype[b];
    const float* fw = fc_w + ((size_t)u * cDM + t) * cDM;
    float a2 = fc_b[u * cDM + t];
    for (int k = 0; k < cDM; ++k) a2 = fmaf(fw[k], ov[k], a2);
    // ln3 (block reduce over 256)
    float s1 = a2, s2 = a2 * a2;
    #pragma unroll
    for (int m = 32; m; m >>= 1){ s1 += __shfl_xor(s1, m); s2 += __shfl_xor(s2, m); }
    if ((t & 63) == 0){ red[t >> 6] = s1; red[4 + (t >> 6)] = s2; }
    __syncthreads();
    s1 = red[0] + red[1] + red[2] + red[3];
    s2 = red[4] + red[5] + red[6] + red[7];
    float mu = s1 * (1.0f / cDM);
    float var = s2 * (1.0f / cDM) - mu * mu;
    float rs = rsqrtf(var + LNEPS);
    cat[t] = (a2 - mu) * rs * g3[t] + b3[t];
    if (t < cD) cat[cDM + t] = src[b * cD + t];
    __syncthreads();
    if (t < cD){
        const float* w1 = m1w + (size_t)t * (cDM + cD);
        float a = m1b[t];
        for (int k = 0; k < cDM + cD; ++k) a = fmaf(w1[k], cat[k], a);
        hm[t] = fmaxf(a, 0.f);
    }
    __syncthreads();
    if (t < cD){
        const float* w2 = m2w + (size_t)t * cD;
        float a = m2b[t];
        #pragma unroll 4
        for (int k = 0; k < cD; ++k) a = fmaf(w2[k], hm[k], a);
        outF[(size_t)b * cD + t] = a;
    }
}

extern "C" void kernel_launch(void* const* d_in, const int* in_sizes, int n_in,
                              void* d_out, int out_size, void* d_ws, size_t ws_size,
                              hipStream_t stream) {
    const float* src    = (const float*)d_in[0];
    const float* src_t  = (const float*)d_in[1];
    const float* seq    = (const float*)d_in[2];
    const float* seq_t  = (const float*)d_in[3];
    const float* seq_e  = (const float*)d_in[4];
    const float* Wq     = (const float*)d_in[5];
    const float* Wk     = (const float*)d_in[6];
    const float* Wv     = (const float*)d_in[7];
    const float* rpri   = (const float*)d_in[8];
    const float* fc_w   = (const float*)d_in[9];
    const float* fc_b   = (const float*)d_in[10];
    const float* ln1g   = (const float*)d_in[11];
    const float* ln1b   = (const float*)d_in[12];
    const float* ln2g   = (const float*)d_in[13];
    const float* ln2b   = (const float*)d_in[14];
    const float* ln3g   = (const float*)d_in[15];
    const float* ln3b   = (const float*)d_in[16];
    const float* m1w    = (const float*)d_in[17];
    const float* m1b    = (const float*)d_in[18];
    const float* m2w    = (const float*)d_in[19];
    const float* m2b    = (const float*)d_in[20];
    const int*  etype   = (const int*)d_in[21];
    const int*  utype   = (const int*)d_in[22];
    const int*  maskp   = (const int*)d_in[24];

    // workspace layout
    float* qcat   = (float*)d_ws;                          // B*DM
    float* Qe     = qcat + (size_t)cB * cDM;               // B*NE*DM
    float* logits = Qe + (size_t)cB * cNE * cDM;           // H*B*N
    bf16*  kvec   = (bf16*)(logits + (size_t)cH * cB * cN);// BN*DM bf16
    bf16*  Vmat   = kvec + (size_t)cBN * cDM;              // BN*DM bf16
    int*   cnt    = (int*)(Vmat + (size_t)cBN * cDM);      // 8
    int*   eidx   = cnt + 8;                               // NE*BN
    int*   tiles  = eidx + (size_t)cNE * cBN;              // MAXTILES
    int*   ntiles = tiles + MAXTILES;                      // 1

    float* outF = (float*)d_out;
    float* outA = outF + (size_t)cB * cD;

    k_init<<<dim3(1), dim3(64), 0, stream>>>(cnt);
    k_qprep<<<dim3(cB / 4), dim3(256), 0, stream>>>(src, src_t, ln1g, ln1b, qcat);
    k_kprep<<<dim3(cBN / 8), dim3(256), 0, stream>>>(seq, seq_t, seq_e, ln2g, ln2b,
                                                     etype, kvec, cnt, eidx);
    k_qe<<<dim3(cB / 8, cNE), dim3(256), 0, stream>>>(qcat, Wq, Qe);
    k_tiles<<<dim3(1), dim3(256), 0, stream>>>(cnt, tiles, ntiles);
    k_heavy<<<dim3(MAXTILES), dim3(256), 0, stream>>>(kvec, Wk, Wv, Qe, rpri, utype,
                                                      maskp, cnt, eidx, tiles, ntiles,
                                                      logits, Vmat);
    k_final<<<dim3(cB), dim3(256), 0, stream>>>(logits, Vmat, src, fc_w, fc_b,
                                                ln3g, ln3b, m1w, m1b, m2w, m2b,
                                                utype, outF, outA);
}

// Round 2
// 1215.423 us; speedup vs baseline: 1.7475x; 1.7475x over previous
//
#include <hip/hip_runtime.h>
#include <hip/hip_bf16.h>

typedef __hip_bfloat16 bf16;
typedef __attribute__((ext_vector_type(8))) __bf16 bf16x8;
typedef __attribute__((ext_vector_type(4))) float f32x4;
typedef __attribute__((ext_vector_type(4))) unsigned int u32x4;

static __device__ __forceinline__ float b2f(bf16 x){ return __bfloat162float(x); }
static __device__ __forceinline__ bf16  f2b(float x){ return __float2bfloat16(x); }

constexpr int cB = 2048, cN = 64, cD = 128, cDM = 256, cH = 8, cNE = 6;
constexpr int cBN = cB * cN;                 // 131072 rows
constexpr float LNEPS = 1e-5f;
constexpr float RSQ32 = 0.17677669529663687f; // 1/sqrt(32)
constexpr int MAXT32 = 4102;                  // sum ceil(cnt[e]/32) <= 4096+5, +1 slack

// ---------------- init: zero etype counters ----------------
__global__ void k_init(int* cnt){ if (threadIdx.x < cNE) cnt[threadIdx.x] = 0; }

// ---------------- convert Wq/Wk/Wv to bf16 ----------------
__global__ __launch_bounds__(256) void k_wconv(const float* __restrict__ Wq,
        const float* __restrict__ Wk, const float* __restrict__ Wv,
        bf16* __restrict__ Wqb, bf16* __restrict__ Wkb, bf16* __restrict__ Wvb){
    int i = blockIdx.x * 256 + threadIdx.x;            // i < 98304 (x4 elems)
    const float* s = blockIdx.y == 0 ? Wq : blockIdx.y == 1 ? Wk : Wv;
    bf16* d = blockIdx.y == 0 ? Wqb : blockIdx.y == 1 ? Wkb : Wvb;
    float4 v = ((const float4*)s)[i];
    union { bf16 h[4]; uint2 u; } p;
    p.h[0] = f2b(v.x); p.h[1] = f2b(v.y); p.h[2] = f2b(v.z); p.h[3] = f2b(v.w);
    *(uint2*)&d[(size_t)i * 4] = p.u;
}

// ---------------- qcatb[b] = bf16([ln1(src[b]), src_t[b]]) ----------------
__global__ __launch_bounds__(256) void k_qprep(const float* __restrict__ src,
        const float* __restrict__ src_t, const float* __restrict__ g1,
        const float* __restrict__ b1, bf16* __restrict__ qcatb){
    int lane = threadIdx.x & 63;
    int b = blockIdx.x * 4 + (threadIdx.x >> 6);
    const float* s = src + b * cD;
    float x0 = s[lane], x1 = s[lane + 64];
    float sm = x0 + x1;
    #pragma unroll
    for (int m = 32; m; m >>= 1) sm += __shfl_xor(sm, m);
    float mu = sm * (1.0f / cD);
    float d0 = x0 - mu, d1 = x1 - mu;
    float vs = d0 * d0 + d1 * d1;
    #pragma unroll
    for (int m = 32; m; m >>= 1) vs += __shfl_xor(vs, m);
    float rs = rsqrtf(vs * (1.0f / cD) + LNEPS);
    bf16* q = qcatb + b * cDM;
    q[lane]        = f2b(d0 * rs * g1[lane] + b1[lane]);
    q[lane + 64]   = f2b(d1 * rs * g1[lane + 64] + b1[lane + 64]);
    q[cD + lane]      = f2b(src_t[b * cD + lane]);
    q[cD + lane + 64] = f2b(src_t[b * cD + lane + 64]);
}

// ------------- kvec[row] = [ln2(seq+seq_e), seq_t]; scatter row into etype list -------------
__global__ __launch_bounds__(256) void k_kprep(const float* __restrict__ seq,
        const float* __restrict__ seq_t, const float* __restrict__ seq_e,
        const float* __restrict__ g2, const float* __restrict__ b2v,
        const int* __restrict__ etype, bf16* __restrict__ kvec,
        int* __restrict__ cnt, int* __restrict__ eidx){
    int l = threadIdx.x & 31;
    int row = blockIdx.x * 8 + (threadIdx.x >> 5);
    const float* sq = seq + row * cD;
    const float* se = seq_e + row * cD;
    float x[4], sm = 0.f;
    #pragma unroll
    for (int j = 0; j < 4; ++j){ x[j] = sq[l + 32 * j] + se[l + 32 * j]; sm += x[j]; }
    #pragma unroll
    for (int m = 16; m; m >>= 1) sm += __shfl_xor(sm, m);
    float mu = sm * (1.0f / cD), vs = 0.f;
    #pragma unroll
    for (int j = 0; j < 4; ++j){ x[j] -= mu; vs += x[j] * x[j]; }
    #pragma unroll
    for (int m = 16; m; m >>= 1) vs += __shfl_xor(vs, m);
    float rs = rsqrtf(vs * (1.0f / cD) + LNEPS);
    bf16* kv = kvec + (size_t)row * cDM;
    #pragma unroll
    for (int j = 0; j < 4; ++j) kv[l + 32 * j] = f2b(x[j] * rs * g2[l + 32 * j] + b2v[l + 32 * j]);
    #pragma unroll
    for (int j = 0; j < 4; ++j) kv[cD + l + 32 * j] = f2b(seq_t[row * cD + l + 32 * j]);
    if (l == 0){
        int e = etype[row];
        int pos = atomicAdd(cnt + e, 1);
        eidx[e * cBN + pos] = row;
    }
}

// ------------- Qe[b][e] = qcat[b] @ Wq[e].T via MFMA (dense, 32 b-rows/block) -------------
__global__ __launch_bounds__(256) void k_gemmQ(const bf16* __restrict__ qcatb,
        const bf16* __restrict__ Wqb, float* __restrict__ Qe){
    int t = threadIdx.x, w = t >> 6, l = t & 63;
    int lr = l & 15, lg4 = l >> 4;
    int b0 = blockIdx.x * 32, e = blockIdx.y;
    const char* A  = (const char*)qcatb + (size_t)b0 * 512;
    const char* Wq = (const char*)(Wqb + (size_t)e * 65536);
    int colbase = w * 64;
    f32x4 acc[2][4] = {};
    #pragma unroll
    for (int ks = 0; ks < 8; ++ks){
        int kb = ks * 64 + lg4 * 16;
        bf16x8 a0 = *(const bf16x8*)(A + (size_t)lr * 512 + kb);
        bf16x8 a1 = *(const bf16x8*)(A + (size_t)(16 + lr) * 512 + kb);
        #pragma unroll
        for (int cf = 0; cf < 4; ++cf){
            bf16x8 bq = *(const bf16x8*)(Wq + (size_t)(colbase + cf * 16 + lr) * 512 + kb);
            acc[0][cf] = __builtin_amdgcn_mfma_f32_16x16x32_bf16(a0, bq, acc[0][cf], 0, 0, 0);
            acc[1][cf] = __builtin_amdgcn_mfma_f32_16x16x32_bf16(a1, bq, acc[1][cf], 0, 0, 0);
        }
    }
    #pragma unroll
    for (int rf = 0; rf < 2; ++rf)
        #pragma unroll
        for (int cf = 0; cf < 4; ++cf)
            #pragma unroll
            for (int j = 0; j < 4; ++j){
                int b = b0 + rf * 16 + lg4 * 4 + j;
                Qe[((size_t)b * cNE + e) * cDM + colbase + cf * 16 + lr] = acc[rf][cf][j];
            }
}

// ------------- build tile list: (e, tile-within-e) packed, 32 rows/tile -------------
__global__ void k_tiles(const int* __restrict__ cnt, int* __restrict__ tiles,
                        int* __restrict__ ntiles){
    __shared__ int off[cNE + 1];
    if (threadIdx.x == 0){
        int s = 0;
        for (int e = 0; e < cNE; ++e){ off[e] = s; s += (cnt[e] + 31) >> 5; }
        off[cNE] = s;
        *ntiles = s;
    }
    __syncthreads();
    int nt = off[cNE];
    for (int i = threadIdx.x; i < nt; i += blockDim.x){
        int e = 0;
        while (off[e + 1] <= i) ++e;
        tiles[i] = (e << 16) | (i - off[e]);
    }
}

// ------------- grouped K/V projection via MFMA + attention logits -------------
// Block: 32 gathered rows x 256 cols, K=256. 4 waves, each owns all 32 rows x 64 cols.
// A (kvec rows) staged in LDS with XOR swizzle; B (Wk/Wv bf16) read direct from L2
// (native [o][i] layout == B-fragment layout). K never materialized: dotted against
// LDS-staged Qe in epilogue -> logits. V repacked via LDS -> coalesced 16B stores.
__global__ __launch_bounds__(256) void k_heavy(const bf16* __restrict__ kvec,
        const bf16* __restrict__ Wkb, const bf16* __restrict__ Wvb,
        const float* __restrict__ Qe, const float* __restrict__ rpri,
        const int* __restrict__ utype, const int* __restrict__ maskp,
        const int* __restrict__ cnt, const int* __restrict__ eidx,
        const int* __restrict__ tiles, const int* __restrict__ ntiles,
        float* __restrict__ logits, bf16* __restrict__ Vmat){
    __shared__ __align__(16) unsigned char Alds[32 * 512];
    __shared__ int s_row[32], s_qo[32], s_msk[32], s_nrr[1];
    __shared__ float s_pri[32];
    __shared__ float s_lg[32 * 8];
    if ((int)blockIdx.x >= *ntiles) return;
    int t = threadIdx.x;
    int info = tiles[blockIdx.x];
    int e = info >> 16, r0 = (info & 0xffff) * 32;
    if (t < 32){
        int ce = cnt[e];
        int nr = min(32, ce - r0);
        int rr = (t < nr) ? r0 + t : r0;       // clamp tail to first row of tile
        int row = eidx[e * cBN + rr];
        s_row[t] = row;
        int b = row >> 6;
        s_qo[t] = (b * cNE + e) * cDM;
        s_pri[t] = rpri[utype[b] * cNE + e];
        s_msk[t] = (t < nr) ? maskp[row] : -1; // -1 => invalid row, skip stores
        if (t == 0) s_nrr[0] = nr;
    }
    __syncthreads();
    // stage A: 32 rows x 512B, 16B chunks, write-side XOR swizzle (G4)
    #pragma unroll
    for (int i = 0; i < 4; ++i){
        int idx = t + i * 256, r = idx >> 5, ck = (idx & 31) * 16;
        u32x4 dv = *(const u32x4*)((const char*)kvec + (size_t)s_row[r] * 512 + ck);
        *(u32x4*)(Alds + r * 512 + (ck ^ ((r & 7) << 4))) = dv;
    }
    __syncthreads();
    int w = t >> 6, l = t & 63;
    int lr = l & 15, lg4 = l >> 4;
    int colbase = w * 64;
    const char* WK = (const char*)(Wkb + (size_t)e * 65536);
    const char* WV = (const char*)(Wvb + (size_t)e * 65536);
    f32x4 aK[2][4] = {}, aV[2][4] = {};
    int arow0 = lr * 512;
    int axor = (lr & 7) << 4;
    #pragma unroll
    for (int ks = 0; ks < 8; ++ks){
        int kb = ks * 64 + lg4 * 16;
        bf16x8 af0 = *(const bf16x8*)(Alds + arow0 + ((kb) ^ axor));
        bf16x8 af1 = *(const bf16x8*)(Alds + arow0 + 16 * 512 + ((kb) ^ axor));
        #pragma unroll
        for (int cf = 0; cf < 4; ++cf){
            size_t boff = (size_t)(colbase + cf * 16 + lr) * 512 + kb;
            bf16x8 bk = *(const bf16x8*)(WK + boff);
            bf16x8 bv = *(const bf16x8*)(WV + boff);
            aK[0][cf] = __builtin_amdgcn_mfma_f32_16x16x32_bf16(af0, bk, aK[0][cf], 0, 0, 0);
            aK[1][cf] = __builtin_amdgcn_mfma_f32_16x16x32_bf16(af1, bk, aK[1][cf], 0, 0, 0);
            aV[0][cf] = __builtin_amdgcn_mfma_f32_16x16x32_bf16(af0, bv, aV[0][cf], 0, 0, 0);
            aV[1][cf] = __builtin_amdgcn_mfma_f32_16x16x32_bf16(af1, bv, aV[1][cf], 0, 0, 0);
        }
    }
    // ---- epilogue 1: logits = (K-tile) . Qe, per head ----
    float* Qef = (float*)Alds;                 // 16 rows x 256 f32 = 16KB
    #pragma unroll
    for (int rf = 0; rf < 2; ++rf){
        __syncthreads();                       // A-reads / prev Qef-reads complete
        #pragma unroll
        for (int i = 0; i < 16; ++i)
            Qef[i * 256 + t] = Qe[s_qo[rf * 16 + i] + t];
        __syncthreads();
        #pragma unroll
        for (int j = 0; j < 4; ++j){
            int rloc = lg4 * 4 + j;            // row within this 16-row block
            const float* qr = Qef + rloc * 256 + colbase + lr;
            float p0 = aK[rf][0][j] * qr[0]  + aK[rf][1][j] * qr[16];
            float p1 = aK[rf][2][j] * qr[32] + aK[rf][3][j] * qr[48];
            p0 += __shfl_xor(p0, 1); p0 += __shfl_xor(p0, 2);
            p0 += __shfl_xor(p0, 4); p0 += __shfl_xor(p0, 8);
            p1 += __shfl_xor(p1, 1); p1 += __shfl_xor(p1, 2);
            p1 += __shfl_xor(p1, 4); p1 += __shfl_xor(p1, 8);
            if (lr == 0){
                int row = rf * 16 + rloc;
                s_lg[row * 8 + 2 * w]     = p0;
                s_lg[row * 8 + 2 * w + 1] = p1;
            }
        }
    }
    __syncthreads();
    // write logits: one (row, head) per thread
    {
        int row = t >> 3, h = t & 7;
        if (s_msk[row] >= 0){
            int grow = s_row[row];
            float lgv = s_msk[row] ? -1e10f : s_lg[row * 8 + h] * s_pri[row] * RSQ32;
            logits[((size_t)h * cB + (grow >> 6)) * cN + (grow & 63)] = lgv;
        }
    }
    // ---- epilogue 2: V repack via LDS, coalesced 16B stores ----
    bf16* Vl = (bf16*)Alds;
    #pragma unroll
    for (int rf = 0; rf < 2; ++rf)
        #pragma unroll
        for (int cf = 0; cf < 4; ++cf)
            #pragma unroll
            for (int j = 0; j < 4; ++j)
                Vl[(rf * 16 + lg4 * 4 + j) * 256 + colbase + cf * 16 + lr] = f2b(aV[rf][cf][j]);
    __syncthreads();
    int nr = s_nrr[0];
    #pragma unroll
    for (int i = 0; i < 4; ++i){
        int idx = t + i * 256, r = idx >> 5, ck = (idx & 31) * 16;
        if (r < nr)
            *(u32x4*)((char*)Vmat + (size_t)s_row[r] * 512 + ck) =
                *(const u32x4*)((const char*)Vl + r * 512 + ck);
    }
}

// ------------- softmax, attn out, V-weighted sum, fc, ln3, mlp -------------
__global__ __launch_bounds__(256) void k_final(const float* __restrict__ logits,
        const bf16* __restrict__ Vmat, const float* __restrict__ src,
        const float* __restrict__ fc_w, const float* __restrict__ fc_b,
        const float* __restrict__ g3, const float* __restrict__ b3,
        const float* __restrict__ m1w, const float* __restrict__ m1b,
        const float* __restrict__ m2w, const float* __restrict__ m2b,
        const int* __restrict__ utype,
        float* __restrict__ outF, float* __restrict__ outA){
    __shared__ float p[cH][cN];
    __shared__ float ov[cDM];
    __shared__ float cat[cDM + cD];
    __shared__ float hm[cD];
    __shared__ float red[8];
    int b = blockIdx.x, t = threadIdx.x;
    int h = t >> 5, i = t & 31;
    const float* lgp = logits + ((size_t)h * cB + b) * cN;
    float l0 = lgp[i], l1 = lgp[i + 32];
    float mx = fmaxf(l0, l1);
    #pragma unroll
    for (int m = 16; m; m >>= 1) mx = fmaxf(mx, __shfl_xor(mx, m));
    float e0 = expf(l0 - mx), e1 = expf(l1 - mx);
    float sm = e0 + e1;
    #pragma unroll
    for (int m = 16; m; m >>= 1) sm += __shfl_xor(sm, m);
    float inv = 1.0f / sm;
    e0 *= inv; e1 *= inv;
    p[h][i] = e0; p[h][i + 32] = e1;
    float* ap = outA + ((size_t)h * cB + b) * cN;
    ap[i] = e0; ap[i + 32] = e1;
    __syncthreads();
    // attn-weighted V: col t belongs to head t>>5
    float acc = 0.f;
    const bf16* vb = Vmat + (size_t)b * cN * cDM + t;
    #pragma unroll 4
    for (int n = 0; n < cN; ++n) acc = fmaf(p[t >> 5][n], b2f(vb[(size_t)n * cDM]), acc);
    ov[t] = acc;
    __syncthreads();
    // fc by utype
    int u = utype[b];
    const float* fw = fc_w + ((size_t)u * cDM + t) * cDM;
    float a2 = fc_b[u * cDM + t];
    for (int k = 0; k < cDM; ++k) a2 = fmaf(fw[k], ov[k], a2);
    // ln3 (block reduce over 256)
    float s1 = a2, s2 = a2 * a2;
    #pragma unroll
    for (int m = 32; m; m >>= 1){ s1 += __shfl_xor(s1, m); s2 += __shfl_xor(s2, m); }
    if ((t & 63) == 0){ red[t >> 6] = s1; red[4 + (t >> 6)] = s2; }
    __syncthreads();
    s1 = red[0] + red[1] + red[2] + red[3];
    s2 = red[4] + red[5] + red[6] + red[7];
    float mu = s1 * (1.0f / cDM);
    float var = s2 * (1.0f / cDM) - mu * mu;
    float rs = rsqrtf(var + LNEPS);
    cat[t] = (a2 - mu) * rs * g3[t] + b3[t];
    if (t < cD) cat[cDM + t] = src[b * cD + t];
    __syncthreads();
    if (t < cD){
        const float* w1 = m1w + (size_t)t * (cDM + cD);
        float a = m1b[t];
        for (int k = 0; k < cDM + cD; ++k) a = fmaf(w1[k], cat[k], a);
        hm[t] = fmaxf(a, 0.f);
    }
    __syncthreads();
    if (t < cD){
        const float* w2 = m2w + (size_t)t * cD;
        float a = m2b[t];
        #pragma unroll 4
        for (int k = 0; k < cD; ++k) a = fmaf(w2[k], hm[k], a);
        outF[(size_t)b * cD + t] = a;
    }
}

extern "C" void kernel_launch(void* const* d_in, const int* in_sizes, int n_in,
                              void* d_out, int out_size, void* d_ws, size_t ws_size,
                              hipStream_t stream) {
    const float* src    = (const float*)d_in[0];
    const float* src_t  = (const float*)d_in[1];
    const float* seq    = (const float*)d_in[2];
    const float* seq_t  = (const float*)d_in[3];
    const float* seq_e  = (const float*)d_in[4];
    const float* Wq     = (const float*)d_in[5];
    const float* Wk     = (const float*)d_in[6];
    const float* Wv     = (const float*)d_in[7];
    const float* rpri   = (const float*)d_in[8];
    const float* fc_w   = (const float*)d_in[9];
    const float* fc_b   = (const float*)d_in[10];
    const float* ln1g   = (const float*)d_in[11];
    const float* ln1b   = (const float*)d_in[12];
    const float* ln2g   = (const float*)d_in[13];
    const float* ln2b   = (const float*)d_in[14];
    const float* ln3g   = (const float*)d_in[15];
    const float* ln3b   = (const float*)d_in[16];
    const float* m1w    = (const float*)d_in[17];
    const float* m1b    = (const float*)d_in[18];
    const float* m2w    = (const float*)d_in[19];
    const float* m2b    = (const float*)d_in[20];
    const int*  etype   = (const int*)d_in[21];
    const int*  utype   = (const int*)d_in[22];
    const int*  maskp   = (const int*)d_in[24];

    // workspace layout (f32 regions first, then bf16, then int)
    float* Qe     = (float*)d_ws;                          // B*NE*DM
    float* logits = Qe + (size_t)cB * cNE * cDM;           // H*B*N
    bf16*  qcatb  = (bf16*)(logits + (size_t)cH * cB * cN);// B*DM
    bf16*  kvec   = qcatb + (size_t)cB * cDM;              // BN*DM
    bf16*  Vmat   = kvec + (size_t)cBN * cDM;              // BN*DM
    bf16*  Wqb    = Vmat + (size_t)cBN * cDM;              // NE*DM*DM
    bf16*  Wkb    = Wqb + (size_t)cNE * cDM * cDM;
    bf16*  Wvb    = Wkb + (size_t)cNE * cDM * cDM;
    int*   cnt    = (int*)(Wvb + (size_t)cNE * cDM * cDM); // 8
    int*   eidx   = cnt + 8;                               // NE*BN
    int*   tiles  = eidx + (size_t)cNE * cBN;              // MAXT32
    int*   ntiles = tiles + MAXT32;                        // 1

    float* outF = (float*)d_out;
    float* outA = outF + (size_t)cB * cD;

    k_init<<<dim3(1), dim3(64), 0, stream>>>(cnt);
    k_wconv<<<dim3(384, 3), dim3(256), 0, stream>>>(Wq, Wk, Wv, Wqb, Wkb, Wvb);
    k_qprep<<<dim3(cB / 4), dim3(256), 0, stream>>>(src, src_t, ln1g, ln1b, qcatb);
    k_kprep<<<dim3(cBN / 8), dim3(256), 0, stream>>>(seq, seq_t, seq_e, ln2g, ln2b,
                                                     etype, kvec, cnt, eidx);
    k_gemmQ<<<dim3(cB / 32, cNE), dim3(256), 0, stream>>>(qcatb, Wqb, Qe);
    k_tiles<<<dim3(1), dim3(256), 0, stream>>>(cnt, tiles, ntiles);
    k_heavy<<<dim3(MAXT32), dim3(256), 0, stream>>>(kvec, Wkb, Wvb, Qe, rpri, utype,
                                                    maskp, cnt, eidx, tiles, ntiles,
                                                    logits, Vmat);
    k_final<<<dim3(cB), dim3(256), 0, stream>>>(logits, Vmat, src, fc_w, fc_b,
                                                ln3g, ln3b, m1w, m1b, m2w, m2b,
                                                utype, outF, outA);
}

// Round 3
// 389.796 us; speedup vs baseline: 5.4489x; 3.1181x over previous
//
#include <hip/hip_runtime.h>
#include <hip/hip_bf16.h>

typedef __hip_bfloat16 bf16;
typedef __attribute__((ext_vector_type(8))) __bf16 bf16x8;
typedef __attribute__((ext_vector_type(4))) float f32x4;
typedef __attribute__((ext_vector_type(4))) unsigned int u32x4;

static __device__ __forceinline__ float b2f(bf16 x){ return __bfloat162float(x); }
static __device__ __forceinline__ bf16  f2b(float x){ return __float2bfloat16(x); }

constexpr int cB = 2048, cN = 64, cD = 128, cDM = 256, cH = 8, cNE = 6;
constexpr int cBN = cB * cN;                 // 131072 rows
constexpr float LNEPS = 1e-5f;
constexpr float RSQ32 = 0.17677669529663687f; // 1/sqrt(32)
constexpr int MAXT32 = 4102;                  // sum ceil(cnt[e]/32) <= 4096+5, +1 slack

// ---------------- init: zero etype counters ----------------
__global__ void k_init(int* cnt){ if (threadIdx.x < cNE) cnt[threadIdx.x] = 0; }

// ---------------- convert Wq/Wk/Wv to bf16 ----------------
__global__ __launch_bounds__(256) void k_wconv(const float* __restrict__ Wq,
        const float* __restrict__ Wk, const float* __restrict__ Wv,
        bf16* __restrict__ Wqb, bf16* __restrict__ Wkb, bf16* __restrict__ Wvb){
    int i = blockIdx.x * 256 + threadIdx.x;            // i < 98304 (x4 elems)
    const float* s = blockIdx.y == 0 ? Wq : blockIdx.y == 1 ? Wk : Wv;
    bf16* d = blockIdx.y == 0 ? Wqb : blockIdx.y == 1 ? Wkb : Wvb;
    float4 v = ((const float4*)s)[i];
    union { bf16 h[4]; uint2 u; } p;
    p.h[0] = f2b(v.x); p.h[1] = f2b(v.y); p.h[2] = f2b(v.z); p.h[3] = f2b(v.w);
    *(uint2*)&d[(size_t)i * 4] = p.u;
}

// ---------------- qcatb[b] = bf16([ln1(src[b]), src_t[b]]) ----------------
__global__ __launch_bounds__(256) void k_qprep(const float* __restrict__ src,
        const float* __restrict__ src_t, const float* __restrict__ g1,
        const float* __restrict__ b1, bf16* __restrict__ qcatb){
    int lane = threadIdx.x & 63;
    int b = blockIdx.x * 4 + (threadIdx.x >> 6);
    const float* s = src + b * cD;
    float x0 = s[lane], x1 = s[lane + 64];
    float sm = x0 + x1;
    #pragma unroll
    for (int m = 32; m; m >>= 1) sm += __shfl_xor(sm, m);
    float mu = sm * (1.0f / cD);
    float d0 = x0 - mu, d1 = x1 - mu;
    float vs = d0 * d0 + d1 * d1;
    #pragma unroll
    for (int m = 32; m; m >>= 1) vs += __shfl_xor(vs, m);
    float rs = rsqrtf(vs * (1.0f / cD) + LNEPS);
    bf16* q = qcatb + b * cDM;
    q[lane]        = f2b(d0 * rs * g1[lane] + b1[lane]);
    q[lane + 64]   = f2b(d1 * rs * g1[lane + 64] + b1[lane + 64]);
    q[cD + lane]      = f2b(src_t[b * cD + lane]);
    q[cD + lane + 64] = f2b(src_t[b * cD + lane + 64]);
}

// ------------- kvec[row] = [ln2(seq+seq_e), seq_t]; hierarchical etype scatter -------------
// 256 rows/block (32 passes x 8 groups of 32 lanes). Per-block LDS histogram,
// ONE global atomic per (block, e) to reserve a range, then scatter indices.
__global__ __launch_bounds__(256) void k_kprep(const float* __restrict__ seq,
        const float* __restrict__ seq_t, const float* __restrict__ seq_e,
        const float* __restrict__ g2, const float* __restrict__ b2v,
        const int* __restrict__ etype, bf16* __restrict__ kvec,
        int* __restrict__ cnt, int* __restrict__ eidx){
    __shared__ int lcnt[cNE];
    __shared__ int base[cNE];
    __shared__ unsigned char le[256];
    __shared__ short lp[256];
    int t = threadIdx.x;
    int l = t & 31, g = t >> 5;
    if (t < cNE) lcnt[t] = 0;
    __syncthreads();
    int row0 = blockIdx.x * 256;
    float gg[4], bb[4];
    #pragma unroll
    for (int j = 0; j < 4; ++j){ gg[j] = g2[l * 4 + j]; bb[j] = b2v[l * 4 + j]; }
    for (int pass = 0; pass < 32; ++pass){
        int lid = pass * 8 + g;
        int row = row0 + lid;
        float4 a = *(const float4*)(seq   + (size_t)row * cD + l * 4);
        float4 eV = *(const float4*)(seq_e + (size_t)row * cD + l * 4);
        float x[4] = {a.x + eV.x, a.y + eV.y, a.z + eV.z, a.w + eV.w};
        float sm = x[0] + x[1] + x[2] + x[3];
        #pragma unroll
        for (int m = 16; m; m >>= 1) sm += __shfl_xor(sm, m);
        float mu = sm * (1.0f / cD), vs = 0.f;
        #pragma unroll
        for (int j = 0; j < 4; ++j){ x[j] -= mu; vs += x[j] * x[j]; }
        #pragma unroll
        for (int m = 16; m; m >>= 1) vs += __shfl_xor(vs, m);
        float rs = rsqrtf(vs * (1.0f / cD) + LNEPS);
        bf16* kv = kvec + (size_t)row * cDM;
        union { bf16 h[4]; uint2 u; } p;
        #pragma unroll
        for (int j = 0; j < 4; ++j) p.h[j] = f2b(x[j] * rs * gg[j] + bb[j]);
        *(uint2*)&kv[l * 4] = p.u;
        float4 tv = *(const float4*)(seq_t + (size_t)row * cD + l * 4);
        p.h[0] = f2b(tv.x); p.h[1] = f2b(tv.y); p.h[2] = f2b(tv.z); p.h[3] = f2b(tv.w);
        *(uint2*)&kv[cD + l * 4] = p.u;
        if (l == 0){
            int e = etype[row];
            int pos = atomicAdd(&lcnt[e], 1);
            le[lid] = (unsigned char)e;
            lp[lid] = (short)pos;
        }
    }
    __syncthreads();
    if (t < cNE) base[t] = atomicAdd(cnt + t, lcnt[t]);
    __syncthreads();
    int e = le[t];
    eidx[e * cBN + base[e] + lp[t]] = row0 + t;
}

// ------------- Qe[b][e] = qcat[b] @ Wq[e].T via MFMA (dense, 32 b-rows/block) -------------
__global__ __launch_bounds__(256) void k_gemmQ(const bf16* __restrict__ qcatb,
        const bf16* __restrict__ Wqb, float* __restrict__ Qe){
    int t = threadIdx.x, w = t >> 6, l = t & 63;
    int lr = l & 15, lg4 = l >> 4;
    int b0 = blockIdx.x * 32, e = blockIdx.y;
    const char* A  = (const char*)qcatb + (size_t)b0 * 512;
    const char* Wq = (const char*)(Wqb + (size_t)e * 65536);
    int colbase = w * 64;
    f32x4 acc[2][4] = {};
    #pragma unroll
    for (int ks = 0; ks < 8; ++ks){
        int kb = ks * 64 + lg4 * 16;
        bf16x8 a0 = *(const bf16x8*)(A + (size_t)lr * 512 + kb);
        bf16x8 a1 = *(const bf16x8*)(A + (size_t)(16 + lr) * 512 + kb);
        #pragma unroll
        for (int cf = 0; cf < 4; ++cf){
            bf16x8 bq = *(const bf16x8*)(Wq + (size_t)(colbase + cf * 16 + lr) * 512 + kb);
            acc[0][cf] = __builtin_amdgcn_mfma_f32_16x16x32_bf16(a0, bq, acc[0][cf], 0, 0, 0);
            acc[1][cf] = __builtin_amdgcn_mfma_f32_16x16x32_bf16(a1, bq, acc[1][cf], 0, 0, 0);
        }
    }
    #pragma unroll
    for (int rf = 0; rf < 2; ++rf)
        #pragma unroll
        for (int cf = 0; cf < 4; ++cf)
            #pragma unroll
            for (int j = 0; j < 4; ++j){
                int b = b0 + rf * 16 + lg4 * 4 + j;
                Qe[((size_t)b * cNE + e) * cDM + colbase + cf * 16 + lr] = acc[rf][cf][j];
            }
}

// ------------- build tile list: (e, tile-within-e) packed, 32 rows/tile -------------
__global__ void k_tiles(const int* __restrict__ cnt, int* __restrict__ tiles,
                        int* __restrict__ ntiles){
    __shared__ int off[cNE + 1];
    if (threadIdx.x == 0){
        int s = 0;
        for (int e = 0; e < cNE; ++e){ off[e] = s; s += (cnt[e] + 31) >> 5; }
        off[cNE] = s;
        *ntiles = s;
    }
    __syncthreads();
    int nt = off[cNE];
    for (int i = threadIdx.x; i < nt; i += blockDim.x){
        int e = 0;
        while (off[e + 1] <= i) ++e;
        tiles[i] = (e << 16) | (i - off[e]);
    }
}

// ------------- grouped K/V projection via MFMA + attention logits -------------
__global__ __launch_bounds__(256) void k_heavy(const bf16* __restrict__ kvec,
        const bf16* __restrict__ Wkb, const bf16* __restrict__ Wvb,
        const float* __restrict__ Qe, const float* __restrict__ rpri,
        const int* __restrict__ utype, const int* __restrict__ maskp,
        const int* __restrict__ cnt, const int* __restrict__ eidx,
        const int* __restrict__ tiles, const int* __restrict__ ntiles,
        float* __restrict__ logits, bf16* __restrict__ Vmat){
    __shared__ __align__(16) unsigned char Alds[32 * 512];
    __shared__ int s_row[32], s_qo[32], s_msk[32], s_nrr[1];
    __shared__ float s_pri[32];
    __shared__ float s_lg[32 * 8];
    if ((int)blockIdx.x >= *ntiles) return;
    int t = threadIdx.x;
    int info = tiles[blockIdx.x];
    int e = info >> 16, r0 = (info & 0xffff) * 32;
    if (t < 32){
        int ce = cnt[e];
        int nr = min(32, ce - r0);
        int rr = (t < nr) ? r0 + t : r0;       // clamp tail to first row of tile
        int row = eidx[e * cBN + rr];
        s_row[t] = row;
        int b = row >> 6;
        s_qo[t] = (b * cNE + e) * cDM;
        s_pri[t] = rpri[utype[b] * cNE + e];
        s_msk[t] = (t < nr) ? maskp[row] : -1; // -1 => invalid row, skip stores
        if (t == 0) s_nrr[0] = nr;
    }
    __syncthreads();
    // stage A: 32 rows x 512B, 16B chunks, write-side XOR swizzle (G4)
    #pragma unroll
    for (int i = 0; i < 4; ++i){
        int idx = t + i * 256, r = idx >> 5, ck = (idx & 31) * 16;
        u32x4 dv = *(const u32x4*)((const char*)kvec + (size_t)s_row[r] * 512 + ck);
        *(u32x4*)(Alds + r * 512 + (ck ^ ((r & 7) << 4))) = dv;
    }
    __syncthreads();
    int w = t >> 6, l = t & 63;
    int lr = l & 15, lg4 = l >> 4;
    int colbase = w * 64;
    const char* WK = (const char*)(Wkb + (size_t)e * 65536);
    const char* WV = (const char*)(Wvb + (size_t)e * 65536);
    f32x4 aK[2][4] = {}, aV[2][4] = {};
    int arow0 = lr * 512;
    int axor = (lr & 7) << 4;
    #pragma unroll
    for (int ks = 0; ks < 8; ++ks){
        int kb = ks * 64 + lg4 * 16;
        bf16x8 af0 = *(const bf16x8*)(Alds + arow0 + ((kb) ^ axor));
        bf16x8 af1 = *(const bf16x8*)(Alds + arow0 + 16 * 512 + ((kb) ^ axor));
        #pragma unroll
        for (int cf = 0; cf < 4; ++cf){
            size_t boff = (size_t)(colbase + cf * 16 + lr) * 512 + kb;
            bf16x8 bk = *(const bf16x8*)(WK + boff);
            bf16x8 bv = *(const bf16x8*)(WV + boff);
            aK[0][cf] = __builtin_amdgcn_mfma_f32_16x16x32_bf16(af0, bk, aK[0][cf], 0, 0, 0);
            aK[1][cf] = __builtin_amdgcn_mfma_f32_16x16x32_bf16(af1, bk, aK[1][cf], 0, 0, 0);
            aV[0][cf] = __builtin_amdgcn_mfma_f32_16x16x32_bf16(af0, bv, aV[0][cf], 0, 0, 0);
            aV[1][cf] = __builtin_amdgcn_mfma_f32_16x16x32_bf16(af1, bv, aV[1][cf], 0, 0, 0);
        }
    }
    // ---- epilogue 1: logits = (K-tile) . Qe, per head ----
    float* Qef = (float*)Alds;                 // 16 rows x 256 f32 = 16KB
    #pragma unroll
    for (int rf = 0; rf < 2; ++rf){
        __syncthreads();                       // A-reads / prev Qef-reads complete
        #pragma unroll
        for (int i = 0; i < 16; ++i)
            Qef[i * 256 + t] = Qe[s_qo[rf * 16 + i] + t];
        __syncthreads();
        #pragma unroll
        for (int j = 0; j < 4; ++j){
            int rloc = lg4 * 4 + j;            // row within this 16-row block
            const float* qr = Qef + rloc * 256 + colbase + lr;
            float p0 = aK[rf][0][j] * qr[0]  + aK[rf][1][j] * qr[16];
            float p1 = aK[rf][2][j] * qr[32] + aK[rf][3][j] * qr[48];
            p0 += __shfl_xor(p0, 1); p0 += __shfl_xor(p0, 2);
            p0 += __shfl_xor(p0, 4); p0 += __shfl_xor(p0, 8);
            p1 += __shfl_xor(p1, 1); p1 += __shfl_xor(p1, 2);
            p1 += __shfl_xor(p1, 4); p1 += __shfl_xor(p1, 8);
            if (lr == 0){
                int row = rf * 16 + rloc;
                s_lg[row * 8 + 2 * w]     = p0;
                s_lg[row * 8 + 2 * w + 1] = p1;
            }
        }
    }
    __syncthreads();
    // write logits: one (row, head) per thread
    {
        int row = t >> 3, h = t & 7;
        if (s_msk[row] >= 0){
            int grow = s_row[row];
            float lgv = s_msk[row] ? -1e10f : s_lg[row * 8 + h] * s_pri[row] * RSQ32;
            logits[((size_t)h * cB + (grow >> 6)) * cN + (grow & 63)] = lgv;
        }
    }
    // ---- epilogue 2: V repack via LDS, coalesced 16B stores ----
    bf16* Vl = (bf16*)Alds;
    #pragma unroll
    for (int rf = 0; rf < 2; ++rf)
        #pragma unroll
        for (int cf = 0; cf < 4; ++cf)
            #pragma unroll
            for (int j = 0; j < 4; ++j)
                Vl[(rf * 16 + lg4 * 4 + j) * 256 + colbase + cf * 16 + lr] = f2b(aV[rf][cf][j]);
    __syncthreads();
    int nr = s_nrr[0];
    #pragma unroll
    for (int i = 0; i < 4; ++i){
        int idx = t + i * 256, r = idx >> 5, ck = (idx & 31) * 16;
        if (r < nr)
            *(u32x4*)((char*)Vmat + (size_t)s_row[r] * 512 + ck) =
                *(const u32x4*)((const char*)Vl + r * 512 + ck);
    }
}

// ------------- softmax, attn out, V-weighted sum, fc, ln3, mlp -------------
__global__ __launch_bounds__(256) void k_final(const float* __restrict__ logits,
        const bf16* __restrict__ Vmat, const float* __restrict__ src,
        const float* __restrict__ fc_w, const float* __restrict__ fc_b,
        const float* __restrict__ g3, const float* __restrict__ b3,
        const float* __restrict__ m1w, const float* __restrict__ m1b,
        const float* __restrict__ m2w, const float* __restrict__ m2b,
        const int* __restrict__ utype,
        float* __restrict__ outF, float* __restrict__ outA){
    __shared__ float p[cH][cN];
    __shared__ float ov[cDM];
    __shared__ float cat[cDM + cD];
    __shared__ float hm[cD];
    __shared__ float red[8];
    int b = blockIdx.x, t = threadIdx.x;
    int h = t >> 5, i = t & 31;
    const float* lgp = logits + ((size_t)h * cB + b) * cN;
    float l0 = lgp[i], l1 = lgp[i + 32];
    float mx = fmaxf(l0, l1);
    #pragma unroll
    for (int m = 16; m; m >>= 1) mx = fmaxf(mx, __shfl_xor(mx, m));
    float e0 = expf(l0 - mx), e1 = expf(l1 - mx);
    float sm = e0 + e1;
    #pragma unroll
    for (int m = 16; m; m >>= 1) sm += __shfl_xor(sm, m);
    float inv = 1.0f / sm;
    e0 *= inv; e1 *= inv;
    p[h][i] = e0; p[h][i + 32] = e1;
    float* ap = outA + ((size_t)h * cB + b) * cN;
    ap[i] = e0; ap[i + 32] = e1;
    __syncthreads();
    // attn-weighted V: col t belongs to head t>>5
    float acc = 0.f;
    const bf16* vb = Vmat + (size_t)b * cN * cDM + t;
    #pragma unroll 4
    for (int n = 0; n < cN; ++n) acc = fmaf(p[t >> 5][n], b2f(vb[(size_t)n * cDM]), acc);
    ov[t] = acc;
    __syncthreads();
    // fc by utype
    int u = utype[b];
    const float* fw = fc_w + ((size_t)u * cDM + t) * cDM;
    float a2 = fc_b[u * cDM + t];
    for (int k = 0; k < cDM; ++k) a2 = fmaf(fw[k], ov[k], a2);
    // ln3 (block reduce over 256)
    float s1 = a2, s2 = a2 * a2;
    #pragma unroll
    for (int m = 32; m; m >>= 1){ s1 += __shfl_xor(s1, m); s2 += __shfl_xor(s2, m); }
    if ((t & 63) == 0){ red[t >> 6] = s1; red[4 + (t >> 6)] = s2; }
    __syncthreads();
    s1 = red[0] + red[1] + red[2] + red[3];
    s2 = red[4] + red[5] + red[6] + red[7];
    float mu = s1 * (1.0f / cDM);
    float var = s2 * (1.0f / cDM) - mu * mu;
    float rs = rsqrtf(var + LNEPS);
    cat[t] = (a2 - mu) * rs * g3[t] + b3[t];
    if (t < cD) cat[cDM + t] = src[b * cD + t];
    __syncthreads();
    if (t < cD){
        const float* w1 = m1w + (size_t)t * (cDM + cD);
        float a = m1b[t];
        for (int k = 0; k < cDM + cD; ++k) a = fmaf(w1[k], cat[k], a);
        hm[t] = fmaxf(a, 0.f);
    }
    __syncthreads();
    if (t < cD){
        const float* w2 = m2w + (size_t)t * cD;
        float a = m2b[t];
        #pragma unroll 4
        for (int k = 0; k < cD; ++k) a = fmaf(w2[k], hm[k], a);
        outF[(size_t)b * cD + t] = a;
    }
}

extern "C" void kernel_launch(void* const* d_in, const int* in_sizes, int n_in,
                              void* d_out, int out_size, void* d_ws, size_t ws_size,
                              hipStream_t stream) {
    const float* src    = (const float*)d_in[0];
    const float* src_t  = (const float*)d_in[1];
    const float* seq    = (const float*)d_in[2];
    const float* seq_t  = (const float*)d_in[3];
    const float* seq_e  = (const float*)d_in[4];
    const float* Wq     = (const float*)d_in[5];
    const float* Wk     = (const float*)d_in[6];
    const float* Wv     = (const float*)d_in[7];
    const float* rpri   = (const float*)d_in[8];
    const float* fc_w   = (const float*)d_in[9];
    const float* fc_b   = (const float*)d_in[10];
    const float* ln1g   = (const float*)d_in[11];
    const float* ln1b   = (const float*)d_in[12];
    const float* ln2g   = (const float*)d_in[13];
    const float* ln2b   = (const float*)d_in[14];
    const float* ln3g   = (const float*)d_in[15];
    const float* ln3b   = (const float*)d_in[16];
    const float* m1w    = (const float*)d_in[17];
    const float* m1b    = (const float*)d_in[18];
    const float* m2w    = (const float*)d_in[19];
    const float* m2b    = (const float*)d_in[20];
    const int*  etype   = (const int*)d_in[21];
    const int*  utype   = (const int*)d_in[22];
    const int*  maskp   = (const int*)d_in[24];

    // workspace layout (f32 regions first, then bf16, then int)
    float* Qe     = (float*)d_ws;                          // B*NE*DM
    float* logits = Qe + (size_t)cB * cNE * cDM;           // H*B*N
    bf16*  qcatb  = (bf16*)(logits + (size_t)cH * cB * cN);// B*DM
    bf16*  kvec   = qcatb + (size_t)cB * cDM;              // BN*DM
    bf16*  Vmat   = kvec + (size_t)cBN * cDM;              // BN*DM
    bf16*  Wqb    = Vmat + (size_t)cBN * cDM;              // NE*DM*DM
    bf16*  Wkb    = Wqb + (size_t)cNE * cDM * cDM;
    bf16*  Wvb    = Wkb + (size_t)cNE * cDM * cDM;
    int*   cnt    = (int*)(Wvb + (size_t)cNE * cDM * cDM); // 8
    int*   eidx   = cnt + 8;                               // NE*BN
    int*   tiles  = eidx + (size_t)cNE * cBN;              // MAXT32
    int*   ntiles = tiles + MAXT32;                        // 1

    float* outF = (float*)d_out;
    float* outA = outF + (size_t)cB * cD;

    k_init<<<dim3(1), dim3(64), 0, stream>>>(cnt);
    k_wconv<<<dim3(384, 3), dim3(256), 0, stream>>>(Wq, Wk, Wv, Wqb, Wkb, Wvb);
    k_qprep<<<dim3(cB / 4), dim3(256), 0, stream>>>(src, src_t, ln1g, ln1b, qcatb);
    k_kprep<<<dim3(cBN / 256), dim3(256), 0, stream>>>(seq, seq_t, seq_e, ln2g, ln2b,
                                                       etype, kvec, cnt, eidx);
    k_gemmQ<<<dim3(cB / 32, cNE), dim3(256), 0, stream>>>(qcatb, Wqb, Qe);
    k_tiles<<<dim3(1), dim3(256), 0, stream>>>(cnt, tiles, ntiles);
    k_heavy<<<dim3(MAXT32), dim3(256), 0, stream>>>(kvec, Wkb, Wvb, Qe, rpri, utype,
                                                    maskp, cnt, eidx, tiles, ntiles,
                                                    logits, Vmat);
    k_final<<<dim3(cB), dim3(256), 0, stream>>>(logits, Vmat, src, fc_w, fc_b,
                                                ln3g, ln3b, m1w, m1b, m2w, m2b,
                                                utype, outF, outA);
}

// Round 4
// 357.550 us; speedup vs baseline: 5.9403x; 1.0902x over previous
//
#include <hip/hip_runtime.h>
#include <hip/hip_bf16.h>

typedef __hip_bfloat16 bf16;
typedef __attribute__((ext_vector_type(8))) __bf16 bf16x8;
typedef __attribute__((ext_vector_type(4))) float f32x4;
typedef __attribute__((ext_vector_type(4))) unsigned int u32x4;

static __device__ __forceinline__ float b2f(bf16 x){ return __bfloat162float(x); }
static __device__ __forceinline__ bf16  f2b(float x){ return __float2bfloat16(x); }

constexpr int cB = 2048, cN = 64, cD = 128, cDM = 256, cH = 8, cNE = 6;
constexpr int cBN = cB * cN;                 // 131072 rows
constexpr float LNEPS = 1e-5f;
constexpr float RSQ32 = 0.17677669529663687f; // 1/sqrt(32)
constexpr int MAXT32 = 4102;                  // sum ceil(cnt[e]/32) <= 4096+5, +1 slack

// ---------------- init: zero etype counters ----------------
__global__ void k_init(int* cnt){ if (threadIdx.x < cNE) cnt[threadIdx.x] = 0; }

// ---------------- convert Wq/Wk/Wv to bf16 ----------------
__global__ __launch_bounds__(256) void k_wconv(const float* __restrict__ Wq,
        const float* __restrict__ Wk, const float* __restrict__ Wv,
        bf16* __restrict__ Wqb, bf16* __restrict__ Wkb, bf16* __restrict__ Wvb){
    int i = blockIdx.x * 256 + threadIdx.x;            // i < 98304 (x4 elems)
    const float* s = blockIdx.y == 0 ? Wq : blockIdx.y == 1 ? Wk : Wv;
    bf16* d = blockIdx.y == 0 ? Wqb : blockIdx.y == 1 ? Wkb : Wvb;
    float4 v = ((const float4*)s)[i];
    union { bf16 h[4]; uint2 u; } p;
    p.h[0] = f2b(v.x); p.h[1] = f2b(v.y); p.h[2] = f2b(v.z); p.h[3] = f2b(v.w);
    *(uint2*)&d[(size_t)i * 4] = p.u;
}

// ---------------- qcatb[b] = bf16([ln1(src[b]), src_t[b]]) ----------------
__global__ __launch_bounds__(256) void k_qprep(const float* __restrict__ src,
        const float* __restrict__ src_t, const float* __restrict__ g1,
        const float* __restrict__ b1, bf16* __restrict__ qcatb){
    int lane = threadIdx.x & 63;
    int b = blockIdx.x * 4 + (threadIdx.x >> 6);
    const float* s = src + b * cD;
    float x0 = s[lane], x1 = s[lane + 64];
    float sm = x0 + x1;
    #pragma unroll
    for (int m = 32; m; m >>= 1) sm += __shfl_xor(sm, m);
    float mu = sm * (1.0f / cD);
    float d0 = x0 - mu, d1 = x1 - mu;
    float vs = d0 * d0 + d1 * d1;
    #pragma unroll
    for (int m = 32; m; m >>= 1) vs += __shfl_xor(vs, m);
    float rs = rsqrtf(vs * (1.0f / cD) + LNEPS);
    bf16* q = qcatb + b * cDM;
    q[lane]        = f2b(d0 * rs * g1[lane] + b1[lane]);
    q[lane + 64]   = f2b(d1 * rs * g1[lane + 64] + b1[lane + 64]);
    q[cD + lane]      = f2b(src_t[b * cD + lane]);
    q[cD + lane + 64] = f2b(src_t[b * cD + lane + 64]);
}

// ------------- kvec[row] = [ln2(seq+seq_e), seq_t]; hierarchical etype scatter -------------
__global__ __launch_bounds__(256) void k_kprep(const float* __restrict__ seq,
        const float* __restrict__ seq_t, const float* __restrict__ seq_e,
        const float* __restrict__ g2, const float* __restrict__ b2v,
        const int* __restrict__ etype, bf16* __restrict__ kvec,
        int* __restrict__ cnt, int* __restrict__ eidx){
    __shared__ int lcnt[cNE];
    __shared__ int base[cNE];
    __shared__ unsigned char le[256];
    __shared__ short lp[256];
    int t = threadIdx.x;
    int l = t & 31, g = t >> 5;
    if (t < cNE) lcnt[t] = 0;
    __syncthreads();
    int row0 = blockIdx.x * 256;
    float gg[4], bb[4];
    #pragma unroll
    for (int j = 0; j < 4; ++j){ gg[j] = g2[l * 4 + j]; bb[j] = b2v[l * 4 + j]; }
    for (int pass = 0; pass < 32; ++pass){
        int lid = pass * 8 + g;
        int row = row0 + lid;
        float4 a = *(const float4*)(seq   + (size_t)row * cD + l * 4);
        float4 eV = *(const float4*)(seq_e + (size_t)row * cD + l * 4);
        float x[4] = {a.x + eV.x, a.y + eV.y, a.z + eV.z, a.w + eV.w};
        float sm = x[0] + x[1] + x[2] + x[3];
        #pragma unroll
        for (int m = 16; m; m >>= 1) sm += __shfl_xor(sm, m);
        float mu = sm * (1.0f / cD), vs = 0.f;
        #pragma unroll
        for (int j = 0; j < 4; ++j){ x[j] -= mu; vs += x[j] * x[j]; }
        #pragma unroll
        for (int m = 16; m; m >>= 1) vs += __shfl_xor(vs, m);
        float rs = rsqrtf(vs * (1.0f / cD) + LNEPS);
        bf16* kv = kvec + (size_t)row * cDM;
        union { bf16 h[4]; uint2 u; } p;
        #pragma unroll
        for (int j = 0; j < 4; ++j) p.h[j] = f2b(x[j] * rs * gg[j] + bb[j]);
        *(uint2*)&kv[l * 4] = p.u;
        float4 tv = *(const float4*)(seq_t + (size_t)row * cD + l * 4);
        p.h[0] = f2b(tv.x); p.h[1] = f2b(tv.y); p.h[2] = f2b(tv.z); p.h[3] = f2b(tv.w);
        *(uint2*)&kv[cD + l * 4] = p.u;
        if (l == 0){
            int e = etype[row];
            int pos = atomicAdd(&lcnt[e], 1);
            le[lid] = (unsigned char)e;
            lp[lid] = (short)pos;
        }
    }
    __syncthreads();
    if (t < cNE) base[t] = atomicAdd(cnt + t, lcnt[t]);
    __syncthreads();
    int e = le[t];
    eidx[e * cBN + base[e] + lp[t]] = row0 + t;
}

// ------------- Qe[b][e] = qcat[b] @ Wq[e].T via MFMA (dense, 32 b-rows/block) -------------
__global__ __launch_bounds__(256) void k_gemmQ(const bf16* __restrict__ qcatb,
        const bf16* __restrict__ Wqb, float* __restrict__ Qe){
    int t = threadIdx.x, w = t >> 6, l = t & 63;
    int lr = l & 15, lg4 = l >> 4;
    int b0 = blockIdx.x * 32, e = blockIdx.y;
    const char* A  = (const char*)qcatb + (size_t)b0 * 512;
    const char* Wq = (const char*)(Wqb + (size_t)e * 65536);
    int colbase = w * 64;
    f32x4 acc[2][4] = {};
    #pragma unroll
    for (int ks = 0; ks < 8; ++ks){
        int kb = ks * 64 + lg4 * 16;
        bf16x8 a0 = *(const bf16x8*)(A + (size_t)lr * 512 + kb);
        bf16x8 a1 = *(const bf16x8*)(A + (size_t)(16 + lr) * 512 + kb);
        #pragma unroll
        for (int cf = 0; cf < 4; ++cf){
            bf16x8 bq = *(const bf16x8*)(Wq + (size_t)(colbase + cf * 16 + lr) * 512 + kb);
            acc[0][cf] = __builtin_amdgcn_mfma_f32_16x16x32_bf16(a0, bq, acc[0][cf], 0, 0, 0);
            acc[1][cf] = __builtin_amdgcn_mfma_f32_16x16x32_bf16(a1, bq, acc[1][cf], 0, 0, 0);
        }
    }
    #pragma unroll
    for (int rf = 0; rf < 2; ++rf)
        #pragma unroll
        for (int cf = 0; cf < 4; ++cf)
            #pragma unroll
            for (int j = 0; j < 4; ++j){
                int b = b0 + rf * 16 + lg4 * 4 + j;
                Qe[((size_t)b * cNE + e) * cDM + colbase + cf * 16 + lr] = acc[rf][cf][j];
            }
}

// ------------- build tile list: (e, tile-within-e) packed, 32 rows/tile -------------
__global__ void k_tiles(const int* __restrict__ cnt, int* __restrict__ tiles,
                        int* __restrict__ ntiles){
    __shared__ int off[cNE + 1];
    if (threadIdx.x == 0){
        int s = 0;
        for (int e = 0; e < cNE; ++e){ off[e] = s; s += (cnt[e] + 31) >> 5; }
        off[cNE] = s;
        *ntiles = s;
    }
    __syncthreads();
    int nt = off[cNE];
    for (int i = threadIdx.x; i < nt; i += blockDim.x){
        int e = 0;
        while (off[e + 1] <= i) ++e;
        tiles[i] = (e << 16) | (i - off[e]);
    }
}

// ------------- grouped K/V projection via MFMA + attention logits (v2) -------------
// 512 threads = 8 waves; wave w owns cols [32w, 32w+32) == head w, all 32 rows.
// Register-double-buffered B (K+V frags), Qe prefetched into registers before
// the (barrier-free) MFMA loop. One barrier before logit write, one before V store.
__global__ __launch_bounds__(512, 3) void k_heavy(const bf16* __restrict__ kvec,
        const bf16* __restrict__ Wkb, const bf16* __restrict__ Wvb,
        const float* __restrict__ Qe, const float* __restrict__ rpri,
        const int* __restrict__ utype, const int* __restrict__ maskp,
        const int* __restrict__ cnt, const int* __restrict__ eidx,
        const int* __restrict__ tiles, const int* __restrict__ ntiles,
        float* __restrict__ logits, bf16* __restrict__ Vmat){
    __shared__ __align__(16) unsigned char Alds[32 * 512];
    __shared__ int s_row[32], s_qo[32], s_msk[32], s_nrr[1];
    __shared__ float s_pri[32];
    __shared__ float s_lg[32 * 8];
    if ((int)blockIdx.x >= *ntiles) return;
    int t = threadIdx.x;
    int info = tiles[blockIdx.x];
    int e = info >> 16, r0 = (info & 0xffff) * 32;
    if (t < 32){
        int ce = cnt[e];
        int nr = min(32, ce - r0);
        int rr = (t < nr) ? r0 + t : r0;       // clamp tail to first row of tile
        int row = eidx[e * cBN + rr];
        s_row[t] = row;
        int b = row >> 6;
        s_qo[t] = (b * cNE + e) * cDM;
        s_pri[t] = rpri[utype[b] * cNE + e];
        s_msk[t] = (t < nr) ? maskp[row] : -1; // -1 => invalid row, skip stores
        if (t == 0) s_nrr[0] = nr;
    }
    __syncthreads();
    int w = t >> 6, l = t & 63;
    int lr = l & 15, lg4 = l >> 4;
    int colbase = w * 32;
    // stage A: 32 rows x 512B, 16B chunks, write-side XOR swizzle
    #pragma unroll
    for (int i = 0; i < 2; ++i){
        int idx = t + i * 512, r = idx >> 5, ck = (idx & 31) * 16;
        u32x4 dv = *(const u32x4*)((const char*)kvec + (size_t)s_row[r] * 512 + ck);
        *(u32x4*)(Alds + r * 512 + (ck ^ ((r & 7) << 4))) = dv;
    }
    // Qe prefetch into registers (in flight during MFMA loop)
    float qreg[2][4][2];
    #pragma unroll
    for (int rf = 0; rf < 2; ++rf)
        #pragma unroll
        for (int j = 0; j < 4; ++j){
            int row = rf * 16 + lg4 * 4 + j;
            const float* qp = Qe + s_qo[row] + colbase + lr;
            qreg[rf][j][0] = qp[0];
            qreg[rf][j][1] = qp[16];
        }
    __syncthreads();                           // A visible in LDS
    const char* WK = (const char*)(Wkb + (size_t)e * 65536);
    const char* WV = (const char*)(Wvb + (size_t)e * 65536);
    f32x4 aK[2][2] = {}, aV[2][2] = {};
    bf16x8 bk[2][2], bv[2][2];                 // [buf][cf]
    int bcol0 = (colbase + lr) * 512;
    int bcol1 = (colbase + 16 + lr) * 512;
    int kb0 = lg4 * 16;
    bk[0][0] = *(const bf16x8*)(WK + bcol0 + kb0);
    bk[0][1] = *(const bf16x8*)(WK + bcol1 + kb0);
    bv[0][0] = *(const bf16x8*)(WV + bcol0 + kb0);
    bv[0][1] = *(const bf16x8*)(WV + bcol1 + kb0);
    int arow0 = lr * 512, axor = (lr & 7) << 4;
    #pragma unroll
    for (int ks = 0; ks < 8; ++ks){
        int cur = ks & 1, nxt = cur ^ 1;
        if (ks < 7){
            int kb = (ks + 1) * 64 + lg4 * 16;
            bk[nxt][0] = *(const bf16x8*)(WK + bcol0 + kb);
            bk[nxt][1] = *(const bf16x8*)(WK + bcol1 + kb);
            bv[nxt][0] = *(const bf16x8*)(WV + bcol0 + kb);
            bv[nxt][1] = *(const bf16x8*)(WV + bcol1 + kb);
        }
        int kb = ks * 64 + lg4 * 16;
        bf16x8 af0 = *(const bf16x8*)(Alds + arow0 + (kb ^ axor));
        bf16x8 af1 = *(const bf16x8*)(Alds + arow0 + 16 * 512 + (kb ^ axor));
        aK[0][0] = __builtin_amdgcn_mfma_f32_16x16x32_bf16(af0, bk[cur][0], aK[0][0], 0, 0, 0);
        aK[0][1] = __builtin_amdgcn_mfma_f32_16x16x32_bf16(af0, bk[cur][1], aK[0][1], 0, 0, 0);
        aK[1][0] = __builtin_amdgcn_mfma_f32_16x16x32_bf16(af1, bk[cur][0], aK[1][0], 0, 0, 0);
        aK[1][1] = __builtin_amdgcn_mfma_f32_16x16x32_bf16(af1, bk[cur][1], aK[1][1], 0, 0, 0);
        aV[0][0] = __builtin_amdgcn_mfma_f32_16x16x32_bf16(af0, bv[cur][0], aV[0][0], 0, 0, 0);
        aV[0][1] = __builtin_amdgcn_mfma_f32_16x16x32_bf16(af0, bv[cur][1], aV[0][1], 0, 0, 0);
        aV[1][0] = __builtin_amdgcn_mfma_f32_16x16x32_bf16(af1, bv[cur][0], aV[1][0], 0, 0, 0);
        aV[1][1] = __builtin_amdgcn_mfma_f32_16x16x32_bf16(af1, bv[cur][1], aV[1][1], 0, 0, 0);
    }
    // ---- epilogue 1: logits. Wave w == head w; reduce over 16 lanes (lr).
    #pragma unroll
    for (int rf = 0; rf < 2; ++rf)
        #pragma unroll
        for (int j = 0; j < 4; ++j){
            float p = aK[rf][0][j] * qreg[rf][j][0] + aK[rf][1][j] * qreg[rf][j][1];
            p += __shfl_xor(p, 1); p += __shfl_xor(p, 2);
            p += __shfl_xor(p, 4); p += __shfl_xor(p, 8);
            if (lr == 0) s_lg[(rf * 16 + lg4 * 4 + j) * 8 + w] = p;
        }
    __syncthreads();                           // s_lg ready; all A-reads retired
    if (t < 256){
        int row = t >> 3, h = t & 7;
        if (s_msk[row] >= 0){
            int grow = s_row[row];
            float lgv = s_msk[row] ? -1e10f : s_lg[row * 8 + h] * s_pri[row] * RSQ32;
            logits[((size_t)h * cB + (grow >> 6)) * cN + (grow & 63)] = lgv;
        }
    }
    // ---- epilogue 2: V repack via LDS (swizzled), coalesced 16B stores ----
    #pragma unroll
    for (int rf = 0; rf < 2; ++rf)
        #pragma unroll
        for (int cf = 0; cf < 2; ++cf)
            #pragma unroll
            for (int j = 0; j < 4; ++j){
                int row = rf * 16 + lg4 * 4 + j;
                int byt = (colbase + cf * 16 + lr) * 2;
                *(bf16*)(Alds + row * 512 + (byt ^ ((row & 7) << 4))) = f2b(aV[rf][cf][j]);
            }
    __syncthreads();
    int nr = s_nrr[0];
    #pragma unroll
    for (int i = 0; i < 2; ++i){
        int idx = t + i * 512, r = idx >> 5, ck = (idx & 31) * 16;
        if (r < nr)
            *(u32x4*)((char*)Vmat + (size_t)s_row[r] * 512 + ck) =
                *(const u32x4*)(Alds + r * 512 + (ck ^ ((r & 7) << 4)));
    }
}

// ------------- softmax, attn out, V-weighted sum, fc, ln3, mlp -------------
__global__ __launch_bounds__(256) void k_final(const float* __restrict__ logits,
        const bf16* __restrict__ Vmat, const float* __restrict__ src,
        const float* __restrict__ fc_w, const float* __restrict__ fc_b,
        const float* __restrict__ g3, const float* __restrict__ b3,
        const float* __restrict__ m1w, const float* __restrict__ m1b,
        const float* __restrict__ m2w, const float* __restrict__ m2b,
        const int* __restrict__ utype,
        float* __restrict__ outF, float* __restrict__ outA){
    __shared__ float p[cH][cN];
    __shared__ __align__(16) float ov[cDM];
    __shared__ __align__(16) float cat[cDM + cD];
    __shared__ __align__(16) float hm[cD];
    __shared__ float red[8];
    int b = blockIdx.x, t = threadIdx.x;
    int h = t >> 5, i = t & 31;
    const float* lgp = logits + ((size_t)h * cB + b) * cN;
    float l0 = lgp[i], l1 = lgp[i + 32];
    float mx = fmaxf(l0, l1);
    #pragma unroll
    for (int m = 16; m; m >>= 1) mx = fmaxf(mx, __shfl_xor(mx, m));
    float e0 = expf(l0 - mx), e1 = expf(l1 - mx);
    float sm = e0 + e1;
    #pragma unroll
    for (int m = 16; m; m >>= 1) sm += __shfl_xor(sm, m);
    float inv = 1.0f / sm;
    e0 *= inv; e1 *= inv;
    p[h][i] = e0; p[h][i + 32] = e1;
    float* ap = outA + ((size_t)h * cB + b) * cN;
    ap[i] = e0; ap[i + 32] = e1;
    __syncthreads();
    // attn-weighted V: col t belongs to head t>>5
    float acc = 0.f;
    const bf16* vb = Vmat + (size_t)b * cN * cDM + t;
    #pragma unroll 4
    for (int n = 0; n < cN; ++n) acc = fmaf(p[t >> 5][n], b2f(vb[(size_t)n * cDM]), acc);
    ov[t] = acc;
    __syncthreads();
    // fc by utype (float4 weight loads)
    int u = utype[b];
    const float4* fw4 = (const float4*)(fc_w + ((size_t)u * cDM + t) * cDM);
    float a2 = fc_b[u * cDM + t];
    #pragma unroll 8
    for (int k = 0; k < cDM / 4; ++k){
        float4 wv = fw4[k];
        float4 o = *(const float4*)&ov[k * 4];
        a2 = fmaf(wv.x, o.x, fmaf(wv.y, o.y, fmaf(wv.z, o.z, fmaf(wv.w, o.w, a2))));
    }
    // ln3 (block reduce over 256)
    float s1 = a2, s2 = a2 * a2;
    #pragma unroll
    for (int m = 32; m; m >>= 1){ s1 += __shfl_xor(s1, m); s2 += __shfl_xor(s2, m); }
    if ((t & 63) == 0){ red[t >> 6] = s1; red[4 + (t >> 6)] = s2; }
    __syncthreads();
    s1 = red[0] + red[1] + red[2] + red[3];
    s2 = red[4] + red[5] + red[6] + red[7];
    float mu = s1 * (1.0f / cDM);
    float var = s2 * (1.0f / cDM) - mu * mu;
    float rs = rsqrtf(var + LNEPS);
    cat[t] = (a2 - mu) * rs * g3[t] + b3[t];
    if (t < cD) cat[cDM + t] = src[b * cD + t];
    __syncthreads();
    if (t < cD){
        const float4* w14 = (const float4*)(m1w + (size_t)t * (cDM + cD));
        float a = m1b[t];
        #pragma unroll 8
        for (int k = 0; k < (cDM + cD) / 4; ++k){
            float4 wv = w14[k];
            float4 o = *(const float4*)&cat[k * 4];
            a = fmaf(wv.x, o.x, fmaf(wv.y, o.y, fmaf(wv.z, o.z, fmaf(wv.w, o.w, a))));
        }
        hm[t] = fmaxf(a, 0.f);
    }
    __syncthreads();
    if (t < cD){
        const float4* w24 = (const float4*)(m2w + (size_t)t * cD);
        float a = m2b[t];
        #pragma unroll 8
        for (int k = 0; k < cD / 4; ++k){
            float4 wv = w24[k];
            float4 o = *(const float4*)&hm[k * 4];
            a = fmaf(wv.x, o.x, fmaf(wv.y, o.y, fmaf(wv.z, o.z, fmaf(wv.w, o.w, a))));
        }
        outF[(size_t)b * cD + t] = a;
    }
}

extern "C" void kernel_launch(void* const* d_in, const int* in_sizes, int n_in,
                              void* d_out, int out_size, void* d_ws, size_t ws_size,
                              hipStream_t stream) {
    const float* src    = (const float*)d_in[0];
    const float* src_t  = (const float*)d_in[1];
    const float* seq    = (const float*)d_in[2];
    const float* seq_t  = (const float*)d_in[3];
    const float* seq_e  = (const float*)d_in[4];
    const float* Wq     = (const float*)d_in[5];
    const float* Wk     = (const float*)d_in[6];
    const float* Wv     = (const float*)d_in[7];
    const float* rpri   = (const float*)d_in[8];
    const float* fc_w   = (const float*)d_in[9];
    const float* fc_b   = (const float*)d_in[10];
    const float* ln1g   = (const float*)d_in[11];
    const float* ln1b   = (const float*)d_in[12];
    const float* ln2g   = (const float*)d_in[13];
    const float* ln2b   = (const float*)d_in[14];
    const float* ln3g   = (const float*)d_in[15];
    const float* ln3b   = (const float*)d_in[16];
    const float* m1w    = (const float*)d_in[17];
    const float* m1b    = (const float*)d_in[18];
    const float* m2w    = (const float*)d_in[19];
    const float* m2b    = (const float*)d_in[20];
    const int*  etype   = (const int*)d_in[21];
    const int*  utype   = (const int*)d_in[22];
    const int*  maskp   = (const int*)d_in[24];

    // workspace layout (f32 regions first, then bf16, then int)
    float* Qe     = (float*)d_ws;                          // B*NE*DM
    float* logits = Qe + (size_t)cB * cNE * cDM;           // H*B*N
    bf16*  qcatb  = (bf16*)(logits + (size_t)cH * cB * cN);// B*DM
    bf16*  kvec   = qcatb + (size_t)cB * cDM;              // BN*DM
    bf16*  Vmat   = kvec + (size_t)cBN * cDM;              // BN*DM
    bf16*  Wqb    = Vmat + (size_t)cBN * cDM;              // NE*DM*DM
    bf16*  Wkb    = Wqb + (size_t)cNE * cDM * cDM;
    bf16*  Wvb    = Wkb + (size_t)cNE * cDM * cDM;
    int*   cnt    = (int*)(Wvb + (size_t)cNE * cDM * cDM); // 8
    int*   eidx   = cnt + 8;                               // NE*BN
    int*   tiles  = eidx + (size_t)cNE * cBN;              // MAXT32
    int*   ntiles = tiles + MAXT32;                        // 1

    float* outF = (float*)d_out;
    float* outA = outF + (size_t)cB * cD;

    k_init<<<dim3(1), dim3(64), 0, stream>>>(cnt);
    k_wconv<<<dim3(384, 3), dim3(256), 0, stream>>>(Wq, Wk, Wv, Wqb, Wkb, Wvb);
    k_qprep<<<dim3(cB / 4), dim3(256), 0, stream>>>(src, src_t, ln1g, ln1b, qcatb);
    k_kprep<<<dim3(cBN / 256), dim3(256), 0, stream>>>(seq, seq_t, seq_e, ln2g, ln2b,
                                                       etype, kvec, cnt, eidx);
    k_gemmQ<<<dim3(cB / 32, cNE), dim3(256), 0, stream>>>(qcatb, Wqb, Qe);
    k_tiles<<<dim3(1), dim3(256), 0, stream>>>(cnt, tiles, ntiles);
    k_heavy<<<dim3(MAXT32), dim3(512), 0, stream>>>(kvec, Wkb, Wvb, Qe, rpri, utype,
                                                    maskp, cnt, eidx, tiles, ntiles,
                                                    logits, Vmat);
    k_final<<<dim3(cB), dim3(256), 0, stream>>>(logits, Vmat, src, fc_w, fc_b,
                                                ln3g, ln3b, m1w, m1b, m2w, m2b,
                                                utype, outF, outA);
}